// Round 1
// baseline (1233.363 us; speedup 1.0000x reference)
//
#include <hip/hip_runtime.h>
#include <hip/hip_bf16.h>

#define N_NODES 30000
#define N_EDGES 1000000
#define N_GRAPHS 256
#define HEADS 8
#define DHEAD 16
#define HIDDEN 128
#define LAYERS 3
#define KPN 17
#define KPE 16
#define NEG_SLOPE 0.2f
#define BN_EPS 1e-5f
#define ET (N_EDGES + N_NODES)

// ---------------- CSR build ----------------
__global__ void k_init_cnt(int* cnt) {
    int i = blockIdx.x * 256 + threadIdx.x;
    if (i < N_NODES) cnt[i] = 1;   // self loop
}

__global__ void k_count(const int* __restrict__ ei, int* __restrict__ cnt) {
    int e = blockIdx.x * 256 + threadIdx.x;
    if (e < N_EDGES) atomicAdd(&cnt[ei[N_EDGES + e]], 1);
}

__global__ __launch_bounds__(1024) void k_scan(const int* __restrict__ cnt,
                                               int* __restrict__ ptr,
                                               int* __restrict__ cur) {
    __shared__ int sdata[1024];
    int t = threadIdx.x;
    const int CH = (N_NODES + 1023) / 1024;  // 30
    int lo = t * CH;
    int hi = lo + CH; if (hi > N_NODES) hi = N_NODES;
    int s = 0;
    for (int i = lo; i < hi; ++i) s += cnt[i];
    sdata[t] = s;
    __syncthreads();
    for (int off = 1; off < 1024; off <<= 1) {
        int v = (t >= off) ? sdata[t - off] : 0;
        __syncthreads();
        sdata[t] += v;
        __syncthreads();
    }
    int base = (t == 0) ? 0 : sdata[t - 1];
    for (int i = lo; i < hi; ++i) {
        ptr[i] = base; cur[i] = base; base += cnt[i];
    }
    if (t == 1023) ptr[N_NODES] = sdata[1023];
}

__global__ void k_fill(const int* __restrict__ ei, int* __restrict__ cur,
                       int* __restrict__ csr_src) {
    int t = blockIdx.x * 256 + threadIdx.x;
    if (t >= ET) return;
    int s, d;
    if (t < N_EDGES) { s = ei[t]; d = ei[N_EDGES + t]; }
    else { s = t - N_EDGES; d = s; }
    int pos = atomicAdd(&cur[d], 1);
    csr_src[pos] = s;
}

// ---------------- input projection ----------------
__global__ void k_inproj(const float* __restrict__ x, const float* __restrict__ kp_emb,
                         const float* __restrict__ w_in, const float* __restrict__ b_in,
                         float* __restrict__ h) {
    int t = blockIdx.x * 256 + threadIdx.x;
    if (t >= N_NODES * HIDDEN) return;
    int c = t & 127, i = t >> 7;
    float acc = b_in[c];
    const float* xi = x + i * 3;
    acc += xi[0] * w_in[0 * 128 + c];
    acc += xi[1] * w_in[1 * 128 + c];
    acc += xi[2] * w_in[2 * 128 + c];
    const float* kp = kp_emb + (i % KPN) * KPE;
#pragma unroll
    for (int k = 0; k < KPE; ++k) acc += kp[k] * w_in[(3 + k) * 128 + c];
    h[t] = acc;
}

// ---------------- dual GEMM: xl = h@wl, xr = h@wr ----------------
// 32 rows per block, 256 threads, each thread 4 rows x 8 cols (of 256 virtual cols)
__global__ __launch_bounds__(256) void k_gemm(const float* __restrict__ h,
                                              const float* __restrict__ wl,
                                              const float* __restrict__ wr,
                                              float* __restrict__ xl,
                                              float* __restrict__ xr) {
    __shared__ float hs[32][130];
    int brow = blockIdx.x * 32;
    int tid = threadIdx.x;
    // stage h tile
#pragma unroll
    for (int j = 0; j < 4; ++j) {
        int idx = (j * 256 + tid) * 4;  // 0..16380
        int r = idx >> 7, c = idx & 127;
        int gr = brow + r;
        float4 v = make_float4(0.f, 0.f, 0.f, 0.f);
        if (gr < N_NODES) v = *(const float4*)(h + gr * 128 + c);
        hs[r][c] = v.x; hs[r][c + 1] = v.y; hs[r][c + 2] = v.z; hs[r][c + 3] = v.w;
    }
    __syncthreads();
    int cg = tid & 31, rg = tid >> 5;
    const float* wbase = (cg < 16) ? (wl + cg * 8) : (wr + (cg - 16) * 8);
    float acc[4][8];
#pragma unroll
    for (int j = 0; j < 4; ++j)
#pragma unroll
        for (int q = 0; q < 8; ++q) acc[j][q] = 0.f;

    for (int k = 0; k < 128; ++k) {
        float4 w0 = *(const float4*)(wbase + k * 128);
        float4 w1 = *(const float4*)(wbase + k * 128 + 4);
        float hv[4];
#pragma unroll
        for (int j = 0; j < 4; ++j) hv[j] = hs[rg * 4 + j][k];
#pragma unroll
        for (int j = 0; j < 4; ++j) {
            acc[j][0] += hv[j] * w0.x; acc[j][1] += hv[j] * w0.y;
            acc[j][2] += hv[j] * w0.z; acc[j][3] += hv[j] * w0.w;
            acc[j][4] += hv[j] * w1.x; acc[j][5] += hv[j] * w1.y;
            acc[j][6] += hv[j] * w1.z; acc[j][7] += hv[j] * w1.w;
        }
    }
#pragma unroll
    for (int j = 0; j < 4; ++j) {
        int gr = brow + rg * 4 + j;
        if (gr >= N_NODES) continue;
        float* dst = (cg < 16) ? (xl + gr * 128 + cg * 8) : (xr + gr * 128 + (cg - 16) * 8);
        float4 o0 = make_float4(acc[j][0], acc[j][1], acc[j][2], acc[j][3]);
        float4 o1 = make_float4(acc[j][4], acc[j][5], acc[j][6], acc[j][7]);
        *(float4*)(dst) = o0;
        *(float4*)(dst + 4) = o1;
    }
}

// ---------------- GATv2 per-node kernel (1 wave per node) ----------------
__global__ __launch_bounds__(256) void k_gat(const float* __restrict__ xl,
                                             const float* __restrict__ xr,
                                             const int* __restrict__ ptr,
                                             const int* __restrict__ csr_src,
                                             const float* __restrict__ att_l,
                                             const float* __restrict__ bias_l,
                                             const float* __restrict__ gamma_l,
                                             const float* __restrict__ beta_l,
                                             const float* __restrict__ mean_l,
                                             const float* __restrict__ var_l,
                                             float* __restrict__ h) {
    int wid = (blockIdx.x * 256 + threadIdx.x) >> 6;
    int lane = threadIdx.x & 63;
    if (wid >= N_NODES) return;
    int i = wid;
    int d0 = 2 * lane;

    float xr0 = xr[i * 128 + d0], xr1 = xr[i * 128 + d0 + 1];
    float a0 = att_l[d0], a1 = att_l[d0 + 1];
    int e0 = ptr[i], e1 = ptr[i + 1];

    // pass 1: per-head max score
    float m = -1e30f;
    for (int e = e0; e < e1; ++e) {
        int s = csr_src[e];
        float2 v = *(const float2*)(xl + s * 128 + d0);
        float z0 = v.x + xr0, z1 = v.y + xr1;
        z0 = z0 > 0.f ? z0 : NEG_SLOPE * z0;
        z1 = z1 > 0.f ? z1 : NEG_SLOPE * z1;
        float p = z0 * a0 + z1 * a1;
        p += __shfl_xor(p, 1);
        p += __shfl_xor(p, 2);
        p += __shfl_xor(p, 4);
        m = fmaxf(m, p);
    }
    // pass 2: softmax-weighted message sum
    float denom = 0.f, acc0 = 0.f, acc1 = 0.f;
    for (int e = e0; e < e1; ++e) {
        int s = csr_src[e];
        float2 v = *(const float2*)(xl + s * 128 + d0);
        float z0 = v.x + xr0, z1 = v.y + xr1;
        float l0 = z0 > 0.f ? z0 : NEG_SLOPE * z0;
        float l1 = z1 > 0.f ? z1 : NEG_SLOPE * z1;
        float p = l0 * a0 + l1 * a1;
        p += __shfl_xor(p, 1);
        p += __shfl_xor(p, 2);
        p += __shfl_xor(p, 4);
        float ex = __expf(p - m);
        denom += ex;
        acc0 += ex * v.x;
        acc1 += ex * v.y;
    }
    float o0 = acc0 / denom + bias_l[d0];
    float o1 = acc1 / denom + bias_l[d0 + 1];
    o0 = fmaxf(o0, 0.f);
    o1 = fmaxf(o1, 0.f);
    o0 = (o0 - mean_l[d0]) * (gamma_l[d0] * rsqrtf(var_l[d0] + BN_EPS)) + beta_l[d0];
    o1 = (o1 - mean_l[d0 + 1]) * (gamma_l[d0 + 1] * rsqrtf(var_l[d0 + 1] + BN_EPS)) + beta_l[d0 + 1];
    float2 hv = *(const float2*)(h + i * 128 + d0);
    hv.x += o0; hv.y += o1;
    *(float2*)(h + i * 128 + d0) = hv;
}

// ---------------- pooling ----------------
__global__ void k_pool(const float* __restrict__ h, const int* __restrict__ batch,
                       float* __restrict__ pool, float* __restrict__ cntg) {
    int t = blockIdx.x * 256 + threadIdx.x;
    if (t >= N_NODES * 32) return;
    int i = t >> 5, q = t & 31;
    int b = batch[i];
    float4 v = *(const float4*)(h + i * 128 + q * 4);
    atomicAdd(&pool[b * 128 + q * 4 + 0], v.x);
    atomicAdd(&pool[b * 128 + q * 4 + 1], v.y);
    atomicAdd(&pool[b * 128 + q * 4 + 2], v.z);
    atomicAdd(&pool[b * 128 + q * 4 + 3], v.w);
    if (q == 0) atomicAdd(&cntg[b], 1.0f);
}

// ---------------- classifier MLP (1 block per graph) ----------------
__global__ __launch_bounds__(256) void k_mlp(const float* __restrict__ pool,
                                             const float* __restrict__ cntg,
                                             const float* __restrict__ w1, const float* __restrict__ b1,
                                             const float* __restrict__ w2, const float* __restrict__ b2,
                                             const float* __restrict__ w3, const float* __restrict__ b3,
                                             float* __restrict__ out) {
    __shared__ float g[128], t1[256], t2[128];
    int b = blockIdx.x, t = threadIdx.x;
    float cnt = fmaxf(cntg[b], 1.0f);
    if (t < 128) g[t] = pool[b * 128 + t] / cnt;
    __syncthreads();
    {
        float acc = b1[t];
        for (int k = 0; k < 128; ++k) acc += g[k] * w1[k * 256 + t];
        t1[t] = acc > 0.f ? acc : expm1f(acc);
    }
    __syncthreads();
    if (t < 128) {
        float acc = b2[t];
        for (int k = 0; k < 256; ++k) acc += t1[k] * w2[k * 128 + t];
        t2[t] = acc > 0.f ? acc : expm1f(acc);
    }
    __syncthreads();
    if (t < 2) {
        float acc = b3[t];
        for (int k = 0; k < 128; ++k) acc += t2[k] * w3[k * 2 + t];
        out[b * 2 + t] = acc;
    }
}

// ---------------- launch ----------------
extern "C" void kernel_launch(void* const* d_in, const int* in_sizes, int n_in,
                              void* d_out, int out_size, void* d_ws, size_t ws_size,
                              hipStream_t stream) {
    const float* x        = (const float*)d_in[0];
    const int*   ei       = (const int*)d_in[1];
    const int*   batch    = (const int*)d_in[2];
    const float* kp_emb   = (const float*)d_in[3];
    const float* w_in     = (const float*)d_in[4];
    const float* b_in     = (const float*)d_in[5];
    const float* w_l      = (const float*)d_in[6];
    const float* w_r      = (const float*)d_in[7];
    const float* att      = (const float*)d_in[8];
    const float* conv_b   = (const float*)d_in[9];
    const float* bn_gamma = (const float*)d_in[10];
    const float* bn_beta  = (const float*)d_in[11];
    const float* bn_mean  = (const float*)d_in[12];
    const float* bn_var   = (const float*)d_in[13];
    const float* w1 = (const float*)d_in[14];
    const float* b1 = (const float*)d_in[15];
    const float* w2 = (const float*)d_in[16];
    const float* b2 = (const float*)d_in[17];
    const float* w3 = (const float*)d_in[18];
    const float* b3 = (const float*)d_in[19];
    float* out = (float*)d_out;

    char* ws = (char*)d_ws;
    const size_t OFF_H    = 0;
    const size_t OFF_XL   = OFF_H + (size_t)N_NODES * 128 * 4;       // 15360000
    const size_t OFF_XR   = OFF_XL + (size_t)N_NODES * 128 * 4;
    const size_t OFF_PTR  = OFF_XR + (size_t)N_NODES * 128 * 4;
    const size_t OFF_CUR  = OFF_PTR + 120320;
    const size_t OFF_CNT  = OFF_CUR + 120320;
    const size_t OFF_SRC  = OFF_CNT + 120320;
    const size_t OFF_POOL = OFF_SRC + 4120064;
    const size_t OFF_CNTG = OFF_POOL + (size_t)N_GRAPHS * 128 * 4;

    float* h      = (float*)(ws + OFF_H);
    float* xl     = (float*)(ws + OFF_XL);
    float* xr     = (float*)(ws + OFF_XR);
    int*   ptr    = (int*)(ws + OFF_PTR);
    int*   cur    = (int*)(ws + OFF_CUR);
    int*   cnt    = (int*)(ws + OFF_CNT);
    int*   csrsrc = (int*)(ws + OFF_SRC);
    float* pool   = (float*)(ws + OFF_POOL);
    float* cntg   = (float*)(ws + OFF_CNTG);

    // CSR build (dst -> incoming sources, incl. self loops)
    k_init_cnt<<<(N_NODES + 255) / 256, 256, 0, stream>>>(cnt);
    k_count<<<(N_EDGES + 255) / 256, 256, 0, stream>>>(ei, cnt);
    k_scan<<<1, 1024, 0, stream>>>(cnt, ptr, cur);
    k_fill<<<(ET + 255) / 256, 256, 0, stream>>>(ei, cur, csrsrc);

    // input projection
    k_inproj<<<(N_NODES * 128 + 255) / 256, 256, 0, stream>>>(x, kp_emb, w_in, b_in, h);

    for (int l = 0; l < LAYERS; ++l) {
        const float* wl = w_l + (size_t)l * 128 * 128;
        const float* wr = w_r + (size_t)l * 128 * 128;
        k_gemm<<<(N_NODES + 31) / 32, 256, 0, stream>>>(h, wl, wr, xl, xr);
        k_gat<<<(N_NODES + 3) / 4, 256, 0, stream>>>(
            xl, xr, ptr, csrsrc,
            att + (size_t)l * 128, conv_b + (size_t)l * 128,
            bn_gamma + (size_t)l * 128, bn_beta + (size_t)l * 128,
            bn_mean + (size_t)l * 128, bn_var + (size_t)l * 128, h);
    }

    hipMemsetAsync(pool, 0, (size_t)N_GRAPHS * 128 * 4, stream);
    hipMemsetAsync(cntg, 0, (size_t)N_GRAPHS * 4, stream);
    k_pool<<<(N_NODES * 32 + 255) / 256, 256, 0, stream>>>(h, batch, pool, cntg);
    k_mlp<<<N_GRAPHS, 256, 0, stream>>>(pool, cntg, w1, b1, w2, b2, w3, b3, out);
}

// Round 2
// 727.651 us; speedup vs baseline: 1.6950x; 1.6950x over previous
//
#include <hip/hip_runtime.h>
#include <hip/hip_bf16.h>

#define N_NODES 30000
#define N_EDGES 1000000
#define N_GRAPHS 256
#define HEADS 8
#define DHEAD 16
#define HIDDEN 128
#define LAYERS 3
#define KPN 17
#define KPE 16
#define NEG_SLOPE 0.2f
#define BN_EPS 1e-5f
#define ET (N_EDGES + N_NODES)

// ---------------- CSR build ----------------
__global__ void k_init_cnt(int* cnt) {
    int i = blockIdx.x * 256 + threadIdx.x;
    if (i < N_NODES) cnt[i] = 1;   // self loop
}

__global__ void k_count(const int* __restrict__ ei, int* __restrict__ cnt) {
    int e = blockIdx.x * 256 + threadIdx.x;
    if (e < N_EDGES) atomicAdd(&cnt[ei[N_EDGES + e]], 1);
}

__global__ __launch_bounds__(1024) void k_scan(const int* __restrict__ cnt,
                                               int* __restrict__ ptr,
                                               int* __restrict__ cur) {
    __shared__ int sdata[1024];
    int t = threadIdx.x;
    const int CH = (N_NODES + 1023) / 1024;  // 30
    int lo = t * CH;
    int hi = lo + CH; if (hi > N_NODES) hi = N_NODES;
    int s = 0;
    for (int i = lo; i < hi; ++i) s += cnt[i];
    sdata[t] = s;
    __syncthreads();
    for (int off = 1; off < 1024; off <<= 1) {
        int v = (t >= off) ? sdata[t - off] : 0;
        __syncthreads();
        sdata[t] += v;
        __syncthreads();
    }
    int base = (t == 0) ? 0 : sdata[t - 1];
    for (int i = lo; i < hi; ++i) {
        ptr[i] = base; cur[i] = base; base += cnt[i];
    }
    if (t == 1023) ptr[N_NODES] = sdata[1023];
}

__global__ void k_fill(const int* __restrict__ ei, int* __restrict__ cur,
                       int* __restrict__ csr_src) {
    int t = blockIdx.x * 256 + threadIdx.x;
    if (t >= ET) return;
    int s, d;
    if (t < N_EDGES) { s = ei[t]; d = ei[N_EDGES + t]; }
    else { s = t - N_EDGES; d = s; }
    int pos = atomicAdd(&cur[d], 1);
    csr_src[pos] = s;
}

// ---------------- input projection ----------------
__global__ void k_inproj(const float* __restrict__ x, const float* __restrict__ kp_emb,
                         const float* __restrict__ w_in, const float* __restrict__ b_in,
                         float* __restrict__ h) {
    int t = blockIdx.x * 256 + threadIdx.x;
    if (t >= N_NODES * HIDDEN) return;
    int c = t & 127, i = t >> 7;
    float acc = b_in[c];
    const float* xi = x + i * 3;
    acc += xi[0] * w_in[0 * 128 + c];
    acc += xi[1] * w_in[1 * 128 + c];
    acc += xi[2] * w_in[2 * 128 + c];
    const float* kp = kp_emb + (i % KPN) * KPE;
#pragma unroll
    for (int k = 0; k < KPE; ++k) acc += kp[k] * w_in[(3 + k) * 128 + c];
    h[t] = acc;
}

// ---------------- dual GEMM: xl = h@wl, xr = h@wr ----------------
__global__ __launch_bounds__(256) void k_gemm(const float* __restrict__ h,
                                              const float* __restrict__ wl,
                                              const float* __restrict__ wr,
                                              float* __restrict__ xl,
                                              float* __restrict__ xr) {
    __shared__ float hs[32][130];
    int brow = blockIdx.x * 32;
    int tid = threadIdx.x;
#pragma unroll
    for (int j = 0; j < 4; ++j) {
        int idx = (j * 256 + tid) * 4;
        int r = idx >> 7, c = idx & 127;
        int gr = brow + r;
        float4 v = make_float4(0.f, 0.f, 0.f, 0.f);
        if (gr < N_NODES) v = *(const float4*)(h + gr * 128 + c);
        hs[r][c] = v.x; hs[r][c + 1] = v.y; hs[r][c + 2] = v.z; hs[r][c + 3] = v.w;
    }
    __syncthreads();
    int cg = tid & 31, rg = tid >> 5;
    const float* wbase = (cg < 16) ? (wl + cg * 8) : (wr + (cg - 16) * 8);
    float acc[4][8];
#pragma unroll
    for (int j = 0; j < 4; ++j)
#pragma unroll
        for (int q = 0; q < 8; ++q) acc[j][q] = 0.f;

    for (int k = 0; k < 128; ++k) {
        float4 w0 = *(const float4*)(wbase + k * 128);
        float4 w1 = *(const float4*)(wbase + k * 128 + 4);
        float hv[4];
#pragma unroll
        for (int j = 0; j < 4; ++j) hv[j] = hs[rg * 4 + j][k];
#pragma unroll
        for (int j = 0; j < 4; ++j) {
            acc[j][0] += hv[j] * w0.x; acc[j][1] += hv[j] * w0.y;
            acc[j][2] += hv[j] * w0.z; acc[j][3] += hv[j] * w0.w;
            acc[j][4] += hv[j] * w1.x; acc[j][5] += hv[j] * w1.y;
            acc[j][6] += hv[j] * w1.z; acc[j][7] += hv[j] * w1.w;
        }
    }
#pragma unroll
    for (int j = 0; j < 4; ++j) {
        int gr = brow + rg * 4 + j;
        if (gr >= N_NODES) continue;
        float* dst = (cg < 16) ? (xl + gr * 128 + cg * 8) : (xr + gr * 128 + (cg - 16) * 8);
        *(float4*)(dst) = make_float4(acc[j][0], acc[j][1], acc[j][2], acc[j][3]);
        *(float4*)(dst + 4) = make_float4(acc[j][4], acc[j][5], acc[j][6], acc[j][7]);
    }
}

// ---------------- GATv2 per-node kernel (1 wave per node, single-pass online softmax) ----------------
__global__ __launch_bounds__(256) void k_gat(const float* __restrict__ xl,
                                             const float* __restrict__ xr,
                                             const int* __restrict__ ptr,
                                             const int* __restrict__ csr_src,
                                             const float* __restrict__ att_l,
                                             const float* __restrict__ bias_l,
                                             const float* __restrict__ gamma_l,
                                             const float* __restrict__ beta_l,
                                             const float* __restrict__ mean_l,
                                             const float* __restrict__ var_l,
                                             float* __restrict__ h) {
    int wid = (blockIdx.x * 256 + threadIdx.x) >> 6;
    int lane = threadIdx.x & 63;
    if (wid >= N_NODES) return;
    int i = wid;
    int d0 = 2 * lane;

    float xr0 = xr[i * 128 + d0], xr1 = xr[i * 128 + d0 + 1];
    float a0 = att_l[d0], a1 = att_l[d0 + 1];
    int e0 = ptr[i], e1 = ptr[i + 1];

    float m = -1e30f, denom = 0.f, acc0 = 0.f, acc1 = 0.f;

    for (int base = e0; base < e1; base += 64) {
        int idx = base + lane;
        int sv = (idx < e1) ? csr_src[idx] : 0;   // one coalesced index load per 64 edges
        int cnt = e1 - base; if (cnt > 64) cnt = 64;

        // depth-2 software pipeline over the row gathers; scalar (SGPR) row base
        int s0 = __builtin_amdgcn_readfirstlane(__shfl(sv, 0));
        float2 v = *(const float2*)(xl + (size_t)s0 * 128 + d0);
        for (int k = 0; k < cnt; ++k) {
            float2 vn = v;
            if (k + 1 < cnt) {
                int sn = __builtin_amdgcn_readfirstlane(__shfl(sv, k + 1));
                vn = *(const float2*)(xl + (size_t)sn * 128 + d0);
            }
            float z0 = v.x + xr0, z1 = v.y + xr1;
            z0 = z0 > 0.f ? z0 : NEG_SLOPE * z0;
            z1 = z1 > 0.f ? z1 : NEG_SLOPE * z1;
            float p = z0 * a0 + z1 * a1;
            p += __shfl_xor(p, 1);
            p += __shfl_xor(p, 2);
            p += __shfl_xor(p, 4);
            float mn = fmaxf(m, p);
            if (mn > m) {                 // rare after first few edges (per-head-group uniform)
                float c = __expf(m - mn);
                denom *= c; acc0 *= c; acc1 *= c;
                m = mn;
            }
            float ex = __expf(p - m);
            denom += ex;
            acc0 += ex * v.x;
            acc1 += ex * v.y;
            v = vn;
        }
    }

    float o0 = acc0 / denom + bias_l[d0];
    float o1 = acc1 / denom + bias_l[d0 + 1];
    o0 = fmaxf(o0, 0.f);
    o1 = fmaxf(o1, 0.f);
    o0 = (o0 - mean_l[d0]) * (gamma_l[d0] * rsqrtf(var_l[d0] + BN_EPS)) + beta_l[d0];
    o1 = (o1 - mean_l[d0 + 1]) * (gamma_l[d0 + 1] * rsqrtf(var_l[d0 + 1] + BN_EPS)) + beta_l[d0 + 1];
    float2 hv = *(const float2*)(h + i * 128 + d0);
    hv.x += o0; hv.y += o1;
    *(float2*)(h + i * 128 + d0) = hv;
}

// ---------------- pooling ----------------
__global__ void k_pool(const float* __restrict__ h, const int* __restrict__ batch,
                       float* __restrict__ pool, float* __restrict__ cntg) {
    int t = blockIdx.x * 256 + threadIdx.x;
    if (t >= N_NODES * 32) return;
    int i = t >> 5, q = t & 31;
    int b = batch[i];
    float4 v = *(const float4*)(h + i * 128 + q * 4);
    atomicAdd(&pool[b * 128 + q * 4 + 0], v.x);
    atomicAdd(&pool[b * 128 + q * 4 + 1], v.y);
    atomicAdd(&pool[b * 128 + q * 4 + 2], v.z);
    atomicAdd(&pool[b * 128 + q * 4 + 3], v.w);
    if (q == 0) atomicAdd(&cntg[b], 1.0f);
}

// ---------------- classifier MLP (1 block per graph) ----------------
__global__ __launch_bounds__(256) void k_mlp(const float* __restrict__ pool,
                                             const float* __restrict__ cntg,
                                             const float* __restrict__ w1, const float* __restrict__ b1,
                                             const float* __restrict__ w2, const float* __restrict__ b2,
                                             const float* __restrict__ w3, const float* __restrict__ b3,
                                             float* __restrict__ out) {
    __shared__ float g[128], t1[256], t2[128];
    int b = blockIdx.x, t = threadIdx.x;
    float cnt = fmaxf(cntg[b], 1.0f);
    if (t < 128) g[t] = pool[b * 128 + t] / cnt;
    __syncthreads();
    {
        float acc = b1[t];
        for (int k = 0; k < 128; ++k) acc += g[k] * w1[k * 256 + t];
        t1[t] = acc > 0.f ? acc : expm1f(acc);
    }
    __syncthreads();
    if (t < 128) {
        float acc = b2[t];
        for (int k = 0; k < 256; ++k) acc += t1[k] * w2[k * 128 + t];
        t2[t] = acc > 0.f ? acc : expm1f(acc);
    }
    __syncthreads();
    if (t < 2) {
        float acc = b3[t];
        for (int k = 0; k < 128; ++k) acc += t2[k] * w3[k * 2 + t];
        out[b * 2 + t] = acc;
    }
}

// ---------------- launch ----------------
extern "C" void kernel_launch(void* const* d_in, const int* in_sizes, int n_in,
                              void* d_out, int out_size, void* d_ws, size_t ws_size,
                              hipStream_t stream) {
    const float* x        = (const float*)d_in[0];
    const int*   ei       = (const int*)d_in[1];
    const int*   batch    = (const int*)d_in[2];
    const float* kp_emb   = (const float*)d_in[3];
    const float* w_in     = (const float*)d_in[4];
    const float* b_in     = (const float*)d_in[5];
    const float* w_l      = (const float*)d_in[6];
    const float* w_r      = (const float*)d_in[7];
    const float* att      = (const float*)d_in[8];
    const float* conv_b   = (const float*)d_in[9];
    const float* bn_gamma = (const float*)d_in[10];
    const float* bn_beta  = (const float*)d_in[11];
    const float* bn_mean  = (const float*)d_in[12];
    const float* bn_var   = (const float*)d_in[13];
    const float* w1 = (const float*)d_in[14];
    const float* b1 = (const float*)d_in[15];
    const float* w2 = (const float*)d_in[16];
    const float* b2 = (const float*)d_in[17];
    const float* w3 = (const float*)d_in[18];
    const float* b3 = (const float*)d_in[19];
    float* out = (float*)d_out;

    char* ws = (char*)d_ws;
    const size_t OFF_H    = 0;
    const size_t OFF_XL   = OFF_H + (size_t)N_NODES * 128 * 4;
    const size_t OFF_XR   = OFF_XL + (size_t)N_NODES * 128 * 4;
    const size_t OFF_PTR  = OFF_XR + (size_t)N_NODES * 128 * 4;
    const size_t OFF_CUR  = OFF_PTR + 120320;
    const size_t OFF_CNT  = OFF_CUR + 120320;
    const size_t OFF_SRC  = OFF_CNT + 120320;
    const size_t OFF_POOL = OFF_SRC + 4120064;
    const size_t OFF_CNTG = OFF_POOL + (size_t)N_GRAPHS * 128 * 4;

    float* h      = (float*)(ws + OFF_H);
    float* xl     = (float*)(ws + OFF_XL);
    float* xr     = (float*)(ws + OFF_XR);
    int*   ptr    = (int*)(ws + OFF_PTR);
    int*   cur    = (int*)(ws + OFF_CUR);
    int*   cnt    = (int*)(ws + OFF_CNT);
    int*   csrsrc = (int*)(ws + OFF_SRC);
    float* pool   = (float*)(ws + OFF_POOL);
    float* cntg   = (float*)(ws + OFF_CNTG);

    k_init_cnt<<<(N_NODES + 255) / 256, 256, 0, stream>>>(cnt);
    k_count<<<(N_EDGES + 255) / 256, 256, 0, stream>>>(ei, cnt);
    k_scan<<<1, 1024, 0, stream>>>(cnt, ptr, cur);
    k_fill<<<(ET + 255) / 256, 256, 0, stream>>>(ei, cur, csrsrc);

    k_inproj<<<(N_NODES * 128 + 255) / 256, 256, 0, stream>>>(x, kp_emb, w_in, b_in, h);

    for (int l = 0; l < LAYERS; ++l) {
        const float* wl = w_l + (size_t)l * 128 * 128;
        const float* wr = w_r + (size_t)l * 128 * 128;
        k_gemm<<<(N_NODES + 31) / 32, 256, 0, stream>>>(h, wl, wr, xl, xr);
        k_gat<<<(N_NODES + 3) / 4, 256, 0, stream>>>(
            xl, xr, ptr, csrsrc,
            att + (size_t)l * 128, conv_b + (size_t)l * 128,
            bn_gamma + (size_t)l * 128, bn_beta + (size_t)l * 128,
            bn_mean + (size_t)l * 128, bn_var + (size_t)l * 128, h);
    }

    hipMemsetAsync(pool, 0, (size_t)N_GRAPHS * 128 * 4, stream);
    hipMemsetAsync(cntg, 0, (size_t)N_GRAPHS * 4, stream);
    k_pool<<<(N_NODES * 32 + 255) / 256, 256, 0, stream>>>(h, batch, pool, cntg);
    k_mlp<<<N_GRAPHS, 256, 0, stream>>>(pool, cntg, w1, b1, w2, b2, w3, b3, out);
}

// Round 3
// 626.156 us; speedup vs baseline: 1.9697x; 1.1621x over previous
//
#include <hip/hip_runtime.h>
#include <hip/hip_bf16.h>

#define N_NODES 30000
#define N_EDGES 1000000
#define N_GRAPHS 256
#define HEADS 8
#define DHEAD 16
#define HIDDEN 128
#define LAYERS 3
#define KPN 17
#define KPE 16
#define NEG_SLOPE 0.2f
#define BN_EPS 1e-5f
#define ET (N_EDGES + N_NODES)

// ---------------- CSR build ----------------
__global__ void k_init_cnt(int* cnt) {
    int i = blockIdx.x * 256 + threadIdx.x;
    if (i < N_NODES) cnt[i] = 1;   // self loop
}

__global__ void k_count(const int* __restrict__ ei, int* __restrict__ cnt) {
    int e = blockIdx.x * 256 + threadIdx.x;
    if (e < N_EDGES) atomicAdd(&cnt[ei[N_EDGES + e]], 1);
}

__global__ __launch_bounds__(1024) void k_scan(const int* __restrict__ cnt,
                                               int* __restrict__ ptr,
                                               int* __restrict__ cur) {
    __shared__ int sdata[1024];
    int t = threadIdx.x;
    const int CH = (N_NODES + 1023) / 1024;  // 30
    int lo = t * CH;
    int hi = lo + CH; if (hi > N_NODES) hi = N_NODES;
    int s = 0;
    for (int i = lo; i < hi; ++i) s += cnt[i];
    sdata[t] = s;
    __syncthreads();
    for (int off = 1; off < 1024; off <<= 1) {
        int v = (t >= off) ? sdata[t - off] : 0;
        __syncthreads();
        sdata[t] += v;
        __syncthreads();
    }
    int base = (t == 0) ? 0 : sdata[t - 1];
    for (int i = lo; i < hi; ++i) {
        ptr[i] = base; cur[i] = base; base += cnt[i];
    }
    if (t == 1023) ptr[N_NODES] = sdata[1023];
}

__global__ void k_fill(const int* __restrict__ ei, int* __restrict__ cur,
                       int* __restrict__ csr_src) {
    int t = blockIdx.x * 256 + threadIdx.x;
    if (t >= ET) return;
    int s, d;
    if (t < N_EDGES) { s = ei[t]; d = ei[N_EDGES + t]; }
    else { s = t - N_EDGES; d = s; }
    int pos = atomicAdd(&cur[d], 1);
    csr_src[pos] = s;
}

// ---------------- graph segment boundaries (batch is sorted) ----------------
__global__ void k_gptr(const int* __restrict__ batch, int* __restrict__ gptr) {
    int g = blockIdx.x * 256 + threadIdx.x;
    if (g > N_GRAPHS) return;
    if (g == N_GRAPHS) { gptr[g] = N_NODES; return; }
    int lo = 0, hi = N_NODES;
    while (lo < hi) {
        int mid = (lo + hi) >> 1;
        if (batch[mid] < g) lo = mid + 1; else hi = mid;
    }
    gptr[g] = lo;
}

// ---------------- input projection ----------------
__global__ void k_inproj(const float* __restrict__ x, const float* __restrict__ kp_emb,
                         const float* __restrict__ w_in, const float* __restrict__ b_in,
                         float* __restrict__ h) {
    int t = blockIdx.x * 256 + threadIdx.x;
    if (t >= N_NODES * HIDDEN) return;
    int c = t & 127, i = t >> 7;
    float acc = b_in[c];
    const float* xi = x + i * 3;
    acc += xi[0] * w_in[0 * 128 + c];
    acc += xi[1] * w_in[1 * 128 + c];
    acc += xi[2] * w_in[2 * 128 + c];
    const float* kp = kp_emb + (i % KPN) * KPE;
#pragma unroll
    for (int k = 0; k < KPE; ++k) acc += kp[k] * w_in[(3 + k) * 128 + c];
    h[t] = acc;
}

// ---------------- dual GEMM: xl = h@wl, xr = h@wr ----------------
__global__ __launch_bounds__(256) void k_gemm(const float* __restrict__ h,
                                              const float* __restrict__ wl,
                                              const float* __restrict__ wr,
                                              float* __restrict__ xl,
                                              float* __restrict__ xr) {
    __shared__ float hs[32][130];
    int brow = blockIdx.x * 32;
    int tid = threadIdx.x;
#pragma unroll
    for (int j = 0; j < 4; ++j) {
        int idx = (j * 256 + tid) * 4;
        int r = idx >> 7, c = idx & 127;
        int gr = brow + r;
        float4 v = make_float4(0.f, 0.f, 0.f, 0.f);
        if (gr < N_NODES) v = *(const float4*)(h + gr * 128 + c);
        hs[r][c] = v.x; hs[r][c + 1] = v.y; hs[r][c + 2] = v.z; hs[r][c + 3] = v.w;
    }
    __syncthreads();
    int cg = tid & 31, rg = tid >> 5;
    const float* wbase = (cg < 16) ? (wl + cg * 8) : (wr + (cg - 16) * 8);
    float acc[4][8];
#pragma unroll
    for (int j = 0; j < 4; ++j)
#pragma unroll
        for (int q = 0; q < 8; ++q) acc[j][q] = 0.f;

    for (int k = 0; k < 128; ++k) {
        float4 w0 = *(const float4*)(wbase + k * 128);
        float4 w1 = *(const float4*)(wbase + k * 128 + 4);
        float hv[4];
#pragma unroll
        for (int j = 0; j < 4; ++j) hv[j] = hs[rg * 4 + j][k];
#pragma unroll
        for (int j = 0; j < 4; ++j) {
            acc[j][0] += hv[j] * w0.x; acc[j][1] += hv[j] * w0.y;
            acc[j][2] += hv[j] * w0.z; acc[j][3] += hv[j] * w0.w;
            acc[j][4] += hv[j] * w1.x; acc[j][5] += hv[j] * w1.y;
            acc[j][6] += hv[j] * w1.z; acc[j][7] += hv[j] * w1.w;
        }
    }
#pragma unroll
    for (int j = 0; j < 4; ++j) {
        int gr = brow + rg * 4 + j;
        if (gr >= N_NODES) continue;
        float* dst = (cg < 16) ? (xl + gr * 128 + cg * 8) : (xr + gr * 128 + (cg - 16) * 8);
        *(float4*)(dst) = make_float4(acc[j][0], acc[j][1], acc[j][2], acc[j][3]);
        *(float4*)(dst + 4) = make_float4(acc[j][4], acc[j][5], acc[j][6], acc[j][7]);
    }
}

// ---------------- GATv2 per-node kernel (1 wave per node, single-pass online softmax) ----------------
__global__ __launch_bounds__(256) void k_gat(const float* __restrict__ xl,
                                             const float* __restrict__ xr,
                                             const int* __restrict__ ptr,
                                             const int* __restrict__ csr_src,
                                             const float* __restrict__ att_l,
                                             const float* __restrict__ bias_l,
                                             const float* __restrict__ gamma_l,
                                             const float* __restrict__ beta_l,
                                             const float* __restrict__ mean_l,
                                             const float* __restrict__ var_l,
                                             float* __restrict__ h) {
    int wid = (blockIdx.x * 256 + threadIdx.x) >> 6;
    int lane = threadIdx.x & 63;
    if (wid >= N_NODES) return;
    int i = wid;
    int d0 = 2 * lane;

    float xr0 = xr[i * 128 + d0], xr1 = xr[i * 128 + d0 + 1];
    float a0 = att_l[d0], a1 = att_l[d0 + 1];
    int e0 = ptr[i], e1 = ptr[i + 1];

    float m = -1e30f, denom = 0.f, acc0 = 0.f, acc1 = 0.f;

    for (int base = e0; base < e1; base += 64) {
        int idx = base + lane;
        int sv = (idx < e1) ? csr_src[idx] : 0;   // one coalesced index load per 64 edges
        int cnt = e1 - base; if (cnt > 64) cnt = 64;

        int s0 = __builtin_amdgcn_readfirstlane(__shfl(sv, 0));
        float2 v = *(const float2*)(xl + (size_t)s0 * 128 + d0);
        for (int k = 0; k < cnt; ++k) {
            float2 vn = v;
            if (k + 1 < cnt) {
                int sn = __builtin_amdgcn_readfirstlane(__shfl(sv, k + 1));
                vn = *(const float2*)(xl + (size_t)sn * 128 + d0);
            }
            float z0 = v.x + xr0, z1 = v.y + xr1;
            z0 = z0 > 0.f ? z0 : NEG_SLOPE * z0;
            z1 = z1 > 0.f ? z1 : NEG_SLOPE * z1;
            float p = z0 * a0 + z1 * a1;
            p += __shfl_xor(p, 1);
            p += __shfl_xor(p, 2);
            p += __shfl_xor(p, 4);
            float mn = fmaxf(m, p);
            if (mn > m) {
                float c = __expf(m - mn);
                denom *= c; acc0 *= c; acc1 *= c;
                m = mn;
            }
            float ex = __expf(p - m);
            denom += ex;
            acc0 += ex * v.x;
            acc1 += ex * v.y;
            v = vn;
        }
    }

    float o0 = acc0 / denom + bias_l[d0];
    float o1 = acc1 / denom + bias_l[d0 + 1];
    o0 = fmaxf(o0, 0.f);
    o1 = fmaxf(o1, 0.f);
    o0 = (o0 - mean_l[d0]) * (gamma_l[d0] * rsqrtf(var_l[d0] + BN_EPS)) + beta_l[d0];
    o1 = (o1 - mean_l[d0 + 1]) * (gamma_l[d0 + 1] * rsqrtf(var_l[d0 + 1] + BN_EPS)) + beta_l[d0 + 1];
    float2 hv = *(const float2*)(h + i * 128 + d0);
    hv.x += o0; hv.y += o1;
    *(float2*)(h + i * 128 + d0) = hv;
}

// ---------------- pooling: one block per graph, segment sum, no atomics ----------------
__global__ __launch_bounds__(256) void k_pool_seg(const float* __restrict__ h,
                                                  const int* __restrict__ gptr,
                                                  float* __restrict__ pool) {
    __shared__ float red[256];
    int b = blockIdx.x;
    int c = threadIdx.x & 127, half = threadIdx.x >> 7;
    int lo = gptr[b], hi = gptr[b + 1];
    float s = 0.f;
    for (int i = lo + half; i < hi; i += 2) s += h[(size_t)i * 128 + c];
    red[threadIdx.x] = s;
    __syncthreads();
    if (half == 0) pool[b * 128 + c] = red[c] + red[c + 128];
}

// ---------------- classifier MLP (1 block per graph) ----------------
__global__ __launch_bounds__(256) void k_mlp(const float* __restrict__ pool,
                                             const int* __restrict__ gptr,
                                             const float* __restrict__ w1, const float* __restrict__ b1,
                                             const float* __restrict__ w2, const float* __restrict__ b2,
                                             const float* __restrict__ w3, const float* __restrict__ b3,
                                             float* __restrict__ out) {
    __shared__ float g[128], t1[256], t2[128];
    int b = blockIdx.x, t = threadIdx.x;
    float cnt = fmaxf((float)(gptr[b + 1] - gptr[b]), 1.0f);
    if (t < 128) g[t] = pool[b * 128 + t] / cnt;
    __syncthreads();
    {
        float acc = b1[t];
        for (int k = 0; k < 128; ++k) acc += g[k] * w1[k * 256 + t];
        t1[t] = acc > 0.f ? acc : expm1f(acc);
    }
    __syncthreads();
    if (t < 128) {
        float acc = b2[t];
        for (int k = 0; k < 256; ++k) acc += t1[k] * w2[k * 128 + t];
        t2[t] = acc > 0.f ? acc : expm1f(acc);
    }
    __syncthreads();
    if (t < 2) {
        float acc = b3[t];
        for (int k = 0; k < 128; ++k) acc += t2[k] * w3[k * 2 + t];
        out[b * 2 + t] = acc;
    }
}

// ---------------- launch ----------------
extern "C" void kernel_launch(void* const* d_in, const int* in_sizes, int n_in,
                              void* d_out, int out_size, void* d_ws, size_t ws_size,
                              hipStream_t stream) {
    const float* x        = (const float*)d_in[0];
    const int*   ei       = (const int*)d_in[1];
    const int*   batch    = (const int*)d_in[2];
    const float* kp_emb   = (const float*)d_in[3];
    const float* w_in     = (const float*)d_in[4];
    const float* b_in     = (const float*)d_in[5];
    const float* w_l      = (const float*)d_in[6];
    const float* w_r      = (const float*)d_in[7];
    const float* att      = (const float*)d_in[8];
    const float* conv_b   = (const float*)d_in[9];
    const float* bn_gamma = (const float*)d_in[10];
    const float* bn_beta  = (const float*)d_in[11];
    const float* bn_mean  = (const float*)d_in[12];
    const float* bn_var   = (const float*)d_in[13];
    const float* w1 = (const float*)d_in[14];
    const float* b1 = (const float*)d_in[15];
    const float* w2 = (const float*)d_in[16];
    const float* b2 = (const float*)d_in[17];
    const float* w3 = (const float*)d_in[18];
    const float* b3 = (const float*)d_in[19];
    float* out = (float*)d_out;

    char* ws = (char*)d_ws;
    const size_t OFF_H    = 0;
    const size_t OFF_XL   = OFF_H + (size_t)N_NODES * 128 * 4;
    const size_t OFF_XR   = OFF_XL + (size_t)N_NODES * 128 * 4;
    const size_t OFF_PTR  = OFF_XR + (size_t)N_NODES * 128 * 4;
    const size_t OFF_CUR  = OFF_PTR + 120320;
    const size_t OFF_CNT  = OFF_CUR + 120320;
    const size_t OFF_SRC  = OFF_CNT + 120320;
    const size_t OFF_POOL = OFF_SRC + 4120064;
    const size_t OFF_GPTR = OFF_POOL + (size_t)N_GRAPHS * 128 * 4;

    float* h      = (float*)(ws + OFF_H);
    float* xl     = (float*)(ws + OFF_XL);
    float* xr     = (float*)(ws + OFF_XR);
    int*   ptr    = (int*)(ws + OFF_PTR);
    int*   cur    = (int*)(ws + OFF_CUR);
    int*   cnt    = (int*)(ws + OFF_CNT);
    int*   csrsrc = (int*)(ws + OFF_SRC);
    float* pool   = (float*)(ws + OFF_POOL);
    int*   gptr   = (int*)(ws + OFF_GPTR);

    k_init_cnt<<<(N_NODES + 255) / 256, 256, 0, stream>>>(cnt);
    k_count<<<(N_EDGES + 255) / 256, 256, 0, stream>>>(ei, cnt);
    k_scan<<<1, 1024, 0, stream>>>(cnt, ptr, cur);
    k_fill<<<(ET + 255) / 256, 256, 0, stream>>>(ei, cur, csrsrc);
    k_gptr<<<2, 256, 0, stream>>>(batch, gptr);

    k_inproj<<<(N_NODES * 128 + 255) / 256, 256, 0, stream>>>(x, kp_emb, w_in, b_in, h);

    for (int l = 0; l < LAYERS; ++l) {
        const float* wl = w_l + (size_t)l * 128 * 128;
        const float* wr = w_r + (size_t)l * 128 * 128;
        k_gemm<<<(N_NODES + 31) / 32, 256, 0, stream>>>(h, wl, wr, xl, xr);
        k_gat<<<(N_NODES + 3) / 4, 256, 0, stream>>>(
            xl, xr, ptr, csrsrc,
            att + (size_t)l * 128, conv_b + (size_t)l * 128,
            bn_gamma + (size_t)l * 128, bn_beta + (size_t)l * 128,
            bn_mean + (size_t)l * 128, bn_var + (size_t)l * 128, h);
    }

    k_pool_seg<<<N_GRAPHS, 256, 0, stream>>>(h, gptr, pool);
    k_mlp<<<N_GRAPHS, 256, 0, stream>>>(pool, gptr, w1, b1, w2, b2, w3, b3, out);
}

// Round 4
// 488.246 us; speedup vs baseline: 2.5261x; 1.2825x over previous
//
#include <hip/hip_runtime.h>
#include <hip/hip_bf16.h>

#define N_NODES 30000
#define N_EDGES 1000000
#define N_GRAPHS 256
#define HEADS 8
#define DHEAD 16
#define HIDDEN 128
#define LAYERS 3
#define KPN 17
#define KPE 16
#define NEG_SLOPE 0.2f
#define BN_EPS 1e-5f
#define ET (N_EDGES + N_NODES)

// ---------------- CSR build ----------------
__global__ void k_init_cnt(int* cnt) {
    int i = blockIdx.x * 256 + threadIdx.x;
    if (i < N_NODES) cnt[i] = 1;   // self loop
}

__global__ void k_count(const int* __restrict__ ei, int* __restrict__ cnt) {
    int e = blockIdx.x * 256 + threadIdx.x;
    if (e < N_EDGES) atomicAdd(&cnt[ei[N_EDGES + e]], 1);
}

// single block; all traffic staged through LDS, global accesses coalesced
__global__ __launch_bounds__(1024) void k_scan(const int* __restrict__ cnt,
                                               int* __restrict__ ptr,
                                               int* __restrict__ cur) {
    __shared__ int lcnt[N_NODES];
    __shared__ int sums[1024];
    int t = threadIdx.x;
    for (int i = t; i < N_NODES; i += 1024) lcnt[i] = cnt[i];
    __syncthreads();
    const int CH = 30;  // 1024*30 >= 30000
    int lo = t * CH;
    int hi = lo + CH; if (hi > N_NODES) hi = N_NODES;
    int s = 0;
    for (int i = lo; i < hi; ++i) s += lcnt[i];
    sums[t] = s;
    __syncthreads();
    for (int off = 1; off < 1024; off <<= 1) {
        int v = (t >= off) ? sums[t - off] : 0;
        __syncthreads();
        sums[t] += v;
        __syncthreads();
    }
    int base = (t == 0) ? 0 : sums[t - 1];
    for (int i = lo; i < hi; ++i) {
        int c = lcnt[i];
        lcnt[i] = base;   // exclusive prefix
        base += c;
    }
    __syncthreads();
    for (int i = t; i < N_NODES; i += 1024) {
        int v = lcnt[i];
        ptr[i] = v; cur[i] = v;
    }
    if (t == 0) ptr[N_NODES] = ET;
}

__global__ void k_fill(const int* __restrict__ ei, int* __restrict__ cur,
                       int* __restrict__ csr_src) {
    int t = blockIdx.x * 256 + threadIdx.x;
    if (t >= ET) return;
    int s, d;
    if (t < N_EDGES) { s = ei[t]; d = ei[N_EDGES + t]; }
    else { s = t - N_EDGES; d = s; }
    int pos = atomicAdd(&cur[d], 1);
    csr_src[pos] = s;
}

// ---------------- graph segment boundaries (batch is sorted) ----------------
__global__ void k_gptr(const int* __restrict__ batch, int* __restrict__ gptr) {
    int g = blockIdx.x * 256 + threadIdx.x;
    if (g > N_GRAPHS) return;
    if (g == N_GRAPHS) { gptr[g] = N_NODES; return; }
    int lo = 0, hi = N_NODES;
    while (lo < hi) {
        int mid = (lo + hi) >> 1;
        if (batch[mid] < g) lo = mid + 1; else hi = mid;
    }
    gptr[g] = lo;
}

// ---------------- input projection ----------------
__global__ void k_inproj(const float* __restrict__ x, const float* __restrict__ kp_emb,
                         const float* __restrict__ w_in, const float* __restrict__ b_in,
                         float* __restrict__ h) {
    int t = blockIdx.x * 256 + threadIdx.x;
    if (t >= N_NODES * HIDDEN) return;
    int c = t & 127, i = t >> 7;
    float acc = b_in[c];
    const float* xi = x + i * 3;
    acc += xi[0] * w_in[0 * 128 + c];
    acc += xi[1] * w_in[1 * 128 + c];
    acc += xi[2] * w_in[2 * 128 + c];
    const float* kp = kp_emb + (i % KPN) * KPE;
#pragma unroll
    for (int k = 0; k < KPE; ++k) acc += kp[k] * w_in[(3 + k) * 128 + c];
    h[t] = acc;
}

// ---------------- dual GEMM: xl = h@wl, xr = h@wr ----------------
// 64 rows per block, 256 threads, each thread 8 rows x 8 cols (of 256 virtual cols)
__global__ __launch_bounds__(256) void k_gemm(const float* __restrict__ h,
                                              const float* __restrict__ wl,
                                              const float* __restrict__ wr,
                                              float* __restrict__ xl,
                                              float* __restrict__ xr) {
    __shared__ float hs[64][132];   // 132 stride: float4-aligned, 2-way-max bank alias (free)
    int brow = blockIdx.x * 64;
    int tid = threadIdx.x;
#pragma unroll
    for (int j = 0; j < 8; ++j) {
        int flat = j * 256 + tid;            // float4 units, 0..2047
        int r = flat >> 5, c4 = flat & 31;
        int gr = brow + r;
        float4 v = make_float4(0.f, 0.f, 0.f, 0.f);
        if (gr < N_NODES) v = *(const float4*)(h + (size_t)gr * 128 + c4 * 4);
        *(float4*)&hs[r][c4 * 4] = v;
    }
    __syncthreads();
    int cg = tid & 31, rg = tid >> 5;
    const float* wbase = (cg < 16) ? (wl + cg * 8) : (wr + (cg - 16) * 8);
    float acc[8][8];
#pragma unroll
    for (int j = 0; j < 8; ++j)
#pragma unroll
        for (int q = 0; q < 8; ++q) acc[j][q] = 0.f;

    for (int k = 0; k < 128; ++k) {
        float4 w0 = *(const float4*)(wbase + k * 128);
        float4 w1 = *(const float4*)(wbase + k * 128 + 4);
        float hv[8];
#pragma unroll
        for (int j = 0; j < 8; ++j) hv[j] = hs[rg * 8 + j][k];
#pragma unroll
        for (int j = 0; j < 8; ++j) {
            acc[j][0] += hv[j] * w0.x; acc[j][1] += hv[j] * w0.y;
            acc[j][2] += hv[j] * w0.z; acc[j][3] += hv[j] * w0.w;
            acc[j][4] += hv[j] * w1.x; acc[j][5] += hv[j] * w1.y;
            acc[j][6] += hv[j] * w1.z; acc[j][7] += hv[j] * w1.w;
        }
    }
#pragma unroll
    for (int j = 0; j < 8; ++j) {
        int gr = brow + rg * 8 + j;
        if (gr >= N_NODES) continue;
        float* dst = (cg < 16) ? (xl + (size_t)gr * 128 + cg * 8)
                               : (xr + (size_t)gr * 128 + (cg - 16) * 8);
        *(float4*)(dst)     = make_float4(acc[j][0], acc[j][1], acc[j][2], acc[j][3]);
        *(float4*)(dst + 4) = make_float4(acc[j][4], acc[j][5], acc[j][6], acc[j][7]);
    }
}

// ---------------- GATv2 per-node kernel ----------------
// 1 wave per node; no-max softmax (scores bounded << 88); depth-4 gather pipeline
__global__ __launch_bounds__(256) void k_gat(const float* __restrict__ xl,
                                             const float* __restrict__ xr,
                                             const int* __restrict__ ptr,
                                             const int* __restrict__ csr_src,
                                             const float* __restrict__ att_l,
                                             const float* __restrict__ bias_l,
                                             const float* __restrict__ gamma_l,
                                             const float* __restrict__ beta_l,
                                             const float* __restrict__ mean_l,
                                             const float* __restrict__ var_l,
                                             float* __restrict__ h) {
    int wid = (blockIdx.x * 256 + threadIdx.x) >> 6;
    int lane = threadIdx.x & 63;
    if (wid >= N_NODES) return;
    int i = wid;
    int d0 = 2 * lane;

    float xr0 = xr[i * 128 + d0], xr1 = xr[i * 128 + d0 + 1];
    const float L2E = 1.44269504089f;
    float a0 = att_l[d0] * L2E, a1 = att_l[d0 + 1] * L2E;
    int e0 = ptr[i], e1 = ptr[i + 1];

    float denom = 0.f, acc0 = 0.f, acc1 = 0.f;

#define LD(K) (*(const float2*)(xl + ((size_t)__builtin_amdgcn_readfirstlane(__shfl(sv, (K))) << 7) + d0))
#define PROC(VV) { \
    float z0 = VV.x + xr0, z1 = VV.y + xr1; \
    z0 = z0 > 0.f ? z0 : NEG_SLOPE * z0; \
    z1 = z1 > 0.f ? z1 : NEG_SLOPE * z1; \
    float p = z0 * a0 + z1 * a1; \
    p += __shfl_xor(p, 1); \
    p += __shfl_xor(p, 2); \
    p += __shfl_xor(p, 4); \
    float ex = exp2f(p); \
    denom += ex; \
    acc0 += ex * VV.x; \
    acc1 += ex * VV.y; \
}

    for (int base = e0; base < e1; base += 64) {
        int idx = base + lane;
        int sv = (idx < e1) ? csr_src[idx] : 0;   // coalesced; OOB lanes -> row 0 (safe)
        int cnt = e1 - base; if (cnt > 64) cnt = 64;

        float2 c0 = LD(0), c1 = LD(1), c2 = LD(2), c3 = LD(3);
        int kfull = cnt & ~3;
        for (int k = 0; k < kfull; k += 4) {
            float2 n0 = LD(k + 4), n1 = LD(k + 5), n2 = LD(k + 6), n3 = LD(k + 7);
            PROC(c0); PROC(c1); PROC(c2); PROC(c3);
            c0 = n0; c1 = n1; c2 = n2; c3 = n3;
        }
        if (kfull + 0 < cnt) PROC(c0);
        if (kfull + 1 < cnt) PROC(c1);
        if (kfull + 2 < cnt) PROC(c2);
    }
#undef LD
#undef PROC

    float o0 = acc0 / denom + bias_l[d0];
    float o1 = acc1 / denom + bias_l[d0 + 1];
    o0 = fmaxf(o0, 0.f);
    o1 = fmaxf(o1, 0.f);
    o0 = (o0 - mean_l[d0]) * (gamma_l[d0] * rsqrtf(var_l[d0] + BN_EPS)) + beta_l[d0];
    o1 = (o1 - mean_l[d0 + 1]) * (gamma_l[d0 + 1] * rsqrtf(var_l[d0 + 1] + BN_EPS)) + beta_l[d0 + 1];
    float2 hv = *(const float2*)(h + i * 128 + d0);
    hv.x += o0; hv.y += o1;
    *(float2*)(h + i * 128 + d0) = hv;
}

// ---------------- pooling: one block per graph, segment sum, no atomics ----------------
__global__ __launch_bounds__(256) void k_pool_seg(const float* __restrict__ h,
                                                  const int* __restrict__ gptr,
                                                  float* __restrict__ pool) {
    __shared__ float red[256];
    int b = blockIdx.x;
    int c = threadIdx.x & 127, half = threadIdx.x >> 7;
    int lo = gptr[b], hi = gptr[b + 1];
    float s = 0.f;
    for (int i = lo + half; i < hi; i += 2) s += h[(size_t)i * 128 + c];
    red[threadIdx.x] = s;
    __syncthreads();
    if (half == 0) pool[b * 128 + c] = red[c] + red[c + 128];
}

// ---------------- classifier MLP (1 block per graph) ----------------
__global__ __launch_bounds__(256) void k_mlp(const float* __restrict__ pool,
                                             const int* __restrict__ gptr,
                                             const float* __restrict__ w1, const float* __restrict__ b1,
                                             const float* __restrict__ w2, const float* __restrict__ b2,
                                             const float* __restrict__ w3, const float* __restrict__ b3,
                                             float* __restrict__ out) {
    __shared__ float g[128], t1[256], t2[128];
    int b = blockIdx.x, t = threadIdx.x;
    float cnt = fmaxf((float)(gptr[b + 1] - gptr[b]), 1.0f);
    if (t < 128) g[t] = pool[b * 128 + t] / cnt;
    __syncthreads();
    {
        float acc = b1[t];
        for (int k = 0; k < 128; ++k) acc += g[k] * w1[k * 256 + t];
        t1[t] = acc > 0.f ? acc : expm1f(acc);
    }
    __syncthreads();
    if (t < 128) {
        float acc = b2[t];
        for (int k = 0; k < 256; ++k) acc += t1[k] * w2[k * 128 + t];
        t2[t] = acc > 0.f ? acc : expm1f(acc);
    }
    __syncthreads();
    if (t < 2) {
        float acc = b3[t];
        for (int k = 0; k < 128; ++k) acc += t2[k] * w3[k * 2 + t];
        out[b * 2 + t] = acc;
    }
}

// ---------------- launch ----------------
extern "C" void kernel_launch(void* const* d_in, const int* in_sizes, int n_in,
                              void* d_out, int out_size, void* d_ws, size_t ws_size,
                              hipStream_t stream) {
    const float* x        = (const float*)d_in[0];
    const int*   ei       = (const int*)d_in[1];
    const int*   batch    = (const int*)d_in[2];
    const float* kp_emb   = (const float*)d_in[3];
    const float* w_in     = (const float*)d_in[4];
    const float* b_in     = (const float*)d_in[5];
    const float* w_l      = (const float*)d_in[6];
    const float* w_r      = (const float*)d_in[7];
    const float* att      = (const float*)d_in[8];
    const float* conv_b   = (const float*)d_in[9];
    const float* bn_gamma = (const float*)d_in[10];
    const float* bn_beta  = (const float*)d_in[11];
    const float* bn_mean  = (const float*)d_in[12];
    const float* bn_var   = (const float*)d_in[13];
    const float* w1 = (const float*)d_in[14];
    const float* b1 = (const float*)d_in[15];
    const float* w2 = (const float*)d_in[16];
    const float* b2 = (const float*)d_in[17];
    const float* w3 = (const float*)d_in[18];
    const float* b3 = (const float*)d_in[19];
    float* out = (float*)d_out;

    char* ws = (char*)d_ws;
    const size_t OFF_H    = 0;
    const size_t OFF_XL   = OFF_H + (size_t)N_NODES * 128 * 4;
    const size_t OFF_XR   = OFF_XL + (size_t)N_NODES * 128 * 4;
    const size_t OFF_PTR  = OFF_XR + (size_t)N_NODES * 128 * 4;
    const size_t OFF_CUR  = OFF_PTR + 120320;
    const size_t OFF_CNT  = OFF_CUR + 120320;
    const size_t OFF_SRC  = OFF_CNT + 120320;
    const size_t OFF_POOL = OFF_SRC + 4120064;
    const size_t OFF_GPTR = OFF_POOL + (size_t)N_GRAPHS * 128 * 4;

    float* h      = (float*)(ws + OFF_H);
    float* xl     = (float*)(ws + OFF_XL);
    float* xr     = (float*)(ws + OFF_XR);
    int*   ptr    = (int*)(ws + OFF_PTR);
    int*   cur    = (int*)(ws + OFF_CUR);
    int*   cnt    = (int*)(ws + OFF_CNT);
    int*   csrsrc = (int*)(ws + OFF_SRC);
    float* pool   = (float*)(ws + OFF_POOL);
    int*   gptr   = (int*)(ws + OFF_GPTR);

    k_init_cnt<<<(N_NODES + 255) / 256, 256, 0, stream>>>(cnt);
    k_count<<<(N_EDGES + 255) / 256, 256, 0, stream>>>(ei, cnt);
    k_scan<<<1, 1024, 0, stream>>>(cnt, ptr, cur);
    k_fill<<<(ET + 255) / 256, 256, 0, stream>>>(ei, cur, csrsrc);
    k_gptr<<<2, 256, 0, stream>>>(batch, gptr);

    k_inproj<<<(N_NODES * 128 + 255) / 256, 256, 0, stream>>>(x, kp_emb, w_in, b_in, h);

    for (int l = 0; l < LAYERS; ++l) {
        const float* wl = w_l + (size_t)l * 128 * 128;
        const float* wr = w_r + (size_t)l * 128 * 128;
        k_gemm<<<(N_NODES + 63) / 64, 256, 0, stream>>>(h, wl, wr, xl, xr);
        k_gat<<<(N_NODES + 3) / 4, 256, 0, stream>>>(
            xl, xr, ptr, csrsrc,
            att + (size_t)l * 128, conv_b + (size_t)l * 128,
            bn_gamma + (size_t)l * 128, bn_beta + (size_t)l * 128,
            bn_mean + (size_t)l * 128, bn_var + (size_t)l * 128, h);
    }

    k_pool_seg<<<N_GRAPHS, 256, 0, stream>>>(h, gptr, pool);
    k_mlp<<<N_GRAPHS, 256, 0, stream>>>(pool, gptr, w1, b1, w2, b2, w3, b3, out);
}

// Round 5
// 453.302 us; speedup vs baseline: 2.7208x; 1.0771x over previous
//
#include <hip/hip_runtime.h>
#include <hip/hip_bf16.h>

#define N_NODES 30000
#define N_EDGES 1000000
#define N_GRAPHS 256
#define HEADS 8
#define DHEAD 16
#define HIDDEN 128
#define LAYERS 3
#define KPN 17
#define KPE 16
#define NEG_SLOPE 0.2f
#define BN_EPS 1e-5f
#define ET (N_EDGES + N_NODES)

__device__ __forceinline__ unsigned bf16_rne(float f) {
    unsigned u = __float_as_uint(f);
    unsigned r = (u + 0x7fffu + ((u >> 16) & 1u)) >> 16;
    return r;
}

// ---------------- CSR build ----------------
__global__ void k_init_cnt(int* cnt) {
    int i = blockIdx.x * 256 + threadIdx.x;
    if (i < N_NODES) cnt[i] = 1;   // self loop
}

__global__ void k_count(const int* __restrict__ ei, int* __restrict__ cnt) {
    int e = blockIdx.x * 256 + threadIdx.x;
    if (e < N_EDGES) atomicAdd(&cnt[ei[N_EDGES + e]], 1);
}

// single block; all traffic staged through LDS, global accesses coalesced
__global__ __launch_bounds__(1024) void k_scan(const int* __restrict__ cnt,
                                               int* __restrict__ ptr,
                                               int* __restrict__ cur) {
    __shared__ int lcnt[N_NODES];
    __shared__ int sums[1024];
    int t = threadIdx.x;
    for (int i = t; i < N_NODES; i += 1024) lcnt[i] = cnt[i];
    __syncthreads();
    const int CH = 30;
    int lo = t * CH;
    int hi = lo + CH; if (hi > N_NODES) hi = N_NODES;
    int s = 0;
    for (int i = lo; i < hi; ++i) s += lcnt[i];
    sums[t] = s;
    __syncthreads();
    for (int off = 1; off < 1024; off <<= 1) {
        int v = (t >= off) ? sums[t - off] : 0;
        __syncthreads();
        sums[t] += v;
        __syncthreads();
    }
    int base = (t == 0) ? 0 : sums[t - 1];
    for (int i = lo; i < hi; ++i) {
        int c = lcnt[i];
        lcnt[i] = base;
        base += c;
    }
    __syncthreads();
    for (int i = t; i < N_NODES; i += 1024) {
        int v = lcnt[i];
        ptr[i] = v; cur[i] = v;
    }
    if (t == 0) ptr[N_NODES] = ET;
}

__global__ void k_fill(const int* __restrict__ ei, int* __restrict__ cur,
                       int* __restrict__ csr_src) {
    int t = blockIdx.x * 256 + threadIdx.x;
    if (t >= ET) return;
    int s, d;
    if (t < N_EDGES) { s = ei[t]; d = ei[N_EDGES + t]; }
    else { s = t - N_EDGES; d = s; }
    int pos = atomicAdd(&cur[d], 1);
    csr_src[pos] = s;
}

// ---------------- graph segment boundaries (batch is sorted) ----------------
__global__ void k_gptr(const int* __restrict__ batch, int* __restrict__ gptr) {
    int g = blockIdx.x * 256 + threadIdx.x;
    if (g > N_GRAPHS) return;
    if (g == N_GRAPHS) { gptr[g] = N_NODES; return; }
    int lo = 0, hi = N_NODES;
    while (lo < hi) {
        int mid = (lo + hi) >> 1;
        if (batch[mid] < g) lo = mid + 1; else hi = mid;
    }
    gptr[g] = lo;
}

// ---------------- input projection ----------------
__global__ void k_inproj(const float* __restrict__ x, const float* __restrict__ kp_emb,
                         const float* __restrict__ w_in, const float* __restrict__ b_in,
                         float* __restrict__ h) {
    int t = blockIdx.x * 256 + threadIdx.x;
    if (t >= N_NODES * HIDDEN) return;
    int c = t & 127, i = t >> 7;
    float acc = b_in[c];
    const float* xi = x + i * 3;
    acc += xi[0] * w_in[0 * 128 + c];
    acc += xi[1] * w_in[1 * 128 + c];
    acc += xi[2] * w_in[2 * 128 + c];
    const float* kp = kp_emb + (i % KPN) * KPE;
#pragma unroll
    for (int k = 0; k < KPE; ++k) acc += kp[k] * w_in[(3 + k) * 128 + c];
    h[t] = acc;
}

// ---------------- dual GEMM: xl(bf16) = h@wl, xr(f32) = h@wr ----------------
// 64 rows per block, 256 threads, each thread 8 rows x 8 cols (of 256 virtual cols)
__global__ __launch_bounds__(256) void k_gemm(const float* __restrict__ h,
                                              const float* __restrict__ wl,
                                              const float* __restrict__ wr,
                                              unsigned* __restrict__ xlb,   // [N][64] packed bf16x2
                                              float* __restrict__ xr) {
    __shared__ float hs[64][132];
    int brow = blockIdx.x * 64;
    int tid = threadIdx.x;
#pragma unroll
    for (int j = 0; j < 8; ++j) {
        int flat = j * 256 + tid;
        int r = flat >> 5, c4 = flat & 31;
        int gr = brow + r;
        float4 v = make_float4(0.f, 0.f, 0.f, 0.f);
        if (gr < N_NODES) v = *(const float4*)(h + (size_t)gr * 128 + c4 * 4);
        *(float4*)&hs[r][c4 * 4] = v;
    }
    __syncthreads();
    int cg = tid & 31, rg = tid >> 5;
    const float* wbase = (cg < 16) ? (wl + cg * 8) : (wr + (cg - 16) * 8);
    float acc[8][8];
#pragma unroll
    for (int j = 0; j < 8; ++j)
#pragma unroll
        for (int q = 0; q < 8; ++q) acc[j][q] = 0.f;

    for (int k = 0; k < 128; ++k) {
        float4 w0 = *(const float4*)(wbase + k * 128);
        float4 w1 = *(const float4*)(wbase + k * 128 + 4);
        float hv[8];
#pragma unroll
        for (int j = 0; j < 8; ++j) hv[j] = hs[rg * 8 + j][k];
#pragma unroll
        for (int j = 0; j < 8; ++j) {
            acc[j][0] += hv[j] * w0.x; acc[j][1] += hv[j] * w0.y;
            acc[j][2] += hv[j] * w0.z; acc[j][3] += hv[j] * w0.w;
            acc[j][4] += hv[j] * w1.x; acc[j][5] += hv[j] * w1.y;
            acc[j][6] += hv[j] * w1.z; acc[j][7] += hv[j] * w1.w;
        }
    }
#pragma unroll
    for (int j = 0; j < 8; ++j) {
        int gr = brow + rg * 8 + j;
        if (gr >= N_NODES) continue;
        if (cg < 16) {
            // xl -> packed bf16: 8 cols -> 4 dwords
            uint4 o;
            o.x = bf16_rne(acc[j][0]) | (bf16_rne(acc[j][1]) << 16);
            o.y = bf16_rne(acc[j][2]) | (bf16_rne(acc[j][3]) << 16);
            o.z = bf16_rne(acc[j][4]) | (bf16_rne(acc[j][5]) << 16);
            o.w = bf16_rne(acc[j][6]) | (bf16_rne(acc[j][7]) << 16);
            *(uint4*)(xlb + (size_t)gr * 64 + cg * 4) = o;
        } else {
            float* dst = xr + (size_t)gr * 128 + (cg - 16) * 8;
            *(float4*)(dst)     = make_float4(acc[j][0], acc[j][1], acc[j][2], acc[j][3]);
            *(float4*)(dst + 4) = make_float4(acc[j][4], acc[j][5], acc[j][6], acc[j][7]);
        }
    }
}

// ---------------- GATv2 per-node kernel ----------------
// 1 wave per node; no-max softmax; depth-4 gather pipeline; bf16 xl rows (256B)
__global__ __launch_bounds__(256) void k_gat(const unsigned* __restrict__ xlb,
                                             const float* __restrict__ xr,
                                             const int* __restrict__ ptr,
                                             const int* __restrict__ csr_src,
                                             const float* __restrict__ att_l,
                                             const float* __restrict__ bias_l,
                                             const float* __restrict__ gamma_l,
                                             const float* __restrict__ beta_l,
                                             const float* __restrict__ mean_l,
                                             const float* __restrict__ var_l,
                                             float* __restrict__ h) {
    int wid = (blockIdx.x * 256 + threadIdx.x) >> 6;
    int lane = threadIdx.x & 63;
    if (wid >= N_NODES) return;
    int i = wid;
    int d0 = 2 * lane;

    float xr0 = xr[i * 128 + d0], xr1 = xr[i * 128 + d0 + 1];
    const float L2E = 1.44269504089f;
    float a0 = att_l[d0] * L2E, a1 = att_l[d0 + 1] * L2E;
    int e0 = ptr[i], e1 = ptr[i + 1];

    float denom = 0.f, acc0 = 0.f, acc1 = 0.f;

#define LD(K) (xlb[((size_t)__builtin_amdgcn_readfirstlane(__shfl(sv, (K))) << 6) + lane])
#define PROC(WW) { \
    float vx = __uint_as_float((WW) << 16); \
    float vy = __uint_as_float((WW) & 0xffff0000u); \
    float z0 = vx + xr0, z1 = vy + xr1; \
    z0 = fmaxf(z0, NEG_SLOPE * z0); \
    z1 = fmaxf(z1, NEG_SLOPE * z1); \
    float p = z0 * a0 + z1 * a1; \
    p += __shfl_xor(p, 1); \
    p += __shfl_xor(p, 2); \
    p += __shfl_xor(p, 4); \
    float ex = exp2f(p); \
    denom += ex; \
    acc0 += ex * vx; \
    acc1 += ex * vy; \
}

    for (int base = e0; base < e1; base += 64) {
        int idx = base + lane;
        int sv = (idx < e1) ? csr_src[idx] : 0;
        int cnt = e1 - base; if (cnt > 64) cnt = 64;

        unsigned c0 = LD(0), c1 = LD(1), c2 = LD(2), c3 = LD(3);
        int kfull = cnt & ~3;
        for (int k = 0; k < kfull; k += 4) {
            unsigned n0 = LD(k + 4), n1 = LD(k + 5), n2 = LD(k + 6), n3 = LD(k + 7);
            PROC(c0); PROC(c1); PROC(c2); PROC(c3);
            c0 = n0; c1 = n1; c2 = n2; c3 = n3;
        }
        if (kfull + 0 < cnt) PROC(c0);
        if (kfull + 1 < cnt) PROC(c1);
        if (kfull + 2 < cnt) PROC(c2);
    }
#undef LD
#undef PROC

    float o0 = acc0 / denom + bias_l[d0];
    float o1 = acc1 / denom + bias_l[d0 + 1];
    o0 = fmaxf(o0, 0.f);
    o1 = fmaxf(o1, 0.f);
    o0 = (o0 - mean_l[d0]) * (gamma_l[d0] * rsqrtf(var_l[d0] + BN_EPS)) + beta_l[d0];
    o1 = (o1 - mean_l[d0 + 1]) * (gamma_l[d0 + 1] * rsqrtf(var_l[d0 + 1] + BN_EPS)) + beta_l[d0 + 1];
    float2 hv = *(const float2*)(h + i * 128 + d0);
    hv.x += o0; hv.y += o1;
    *(float2*)(h + i * 128 + d0) = hv;
}

// ---------------- pooling: one block per graph, segment sum, no atomics ----------------
__global__ __launch_bounds__(256) void k_pool_seg(const float* __restrict__ h,
                                                  const int* __restrict__ gptr,
                                                  float* __restrict__ pool) {
    __shared__ float red[256];
    int b = blockIdx.x;
    int c = threadIdx.x & 127, half = threadIdx.x >> 7;
    int lo = gptr[b], hi = gptr[b + 1];
    float s = 0.f;
    for (int i = lo + half; i < hi; i += 2) s += h[(size_t)i * 128 + c];
    red[threadIdx.x] = s;
    __syncthreads();
    if (half == 0) pool[b * 128 + c] = red[c] + red[c + 128];
}

// ---------------- classifier MLP (1 block per graph) ----------------
__global__ __launch_bounds__(256) void k_mlp(const float* __restrict__ pool,
                                             const int* __restrict__ gptr,
                                             const float* __restrict__ w1, const float* __restrict__ b1,
                                             const float* __restrict__ w2, const float* __restrict__ b2,
                                             const float* __restrict__ w3, const float* __restrict__ b3,
                                             float* __restrict__ out) {
    __shared__ float g[128], t1[256], t2[128];
    int b = blockIdx.x, t = threadIdx.x;
    float cnt = fmaxf((float)(gptr[b + 1] - gptr[b]), 1.0f);
    if (t < 128) g[t] = pool[b * 128 + t] / cnt;
    __syncthreads();
    {
        float acc = b1[t];
        for (int k = 0; k < 128; ++k) acc += g[k] * w1[k * 256 + t];
        t1[t] = acc > 0.f ? acc : expm1f(acc);
    }
    __syncthreads();
    if (t < 128) {
        float acc = b2[t];
        for (int k = 0; k < 256; ++k) acc += t1[k] * w2[k * 128 + t];
        t2[t] = acc > 0.f ? acc : expm1f(acc);
    }
    __syncthreads();
    if (t < 2) {
        float acc = b3[t];
        for (int k = 0; k < 128; ++k) acc += t2[k] * w3[k * 2 + t];
        out[b * 2 + t] = acc;
    }
}

// ---------------- launch ----------------
extern "C" void kernel_launch(void* const* d_in, const int* in_sizes, int n_in,
                              void* d_out, int out_size, void* d_ws, size_t ws_size,
                              hipStream_t stream) {
    const float* x        = (const float*)d_in[0];
    const int*   ei       = (const int*)d_in[1];
    const int*   batch    = (const int*)d_in[2];
    const float* kp_emb   = (const float*)d_in[3];
    const float* w_in     = (const float*)d_in[4];
    const float* b_in     = (const float*)d_in[5];
    const float* w_l      = (const float*)d_in[6];
    const float* w_r      = (const float*)d_in[7];
    const float* att      = (const float*)d_in[8];
    const float* conv_b   = (const float*)d_in[9];
    const float* bn_gamma = (const float*)d_in[10];
    const float* bn_beta  = (const float*)d_in[11];
    const float* bn_mean  = (const float*)d_in[12];
    const float* bn_var   = (const float*)d_in[13];
    const float* w1 = (const float*)d_in[14];
    const float* b1 = (const float*)d_in[15];
    const float* w2 = (const float*)d_in[16];
    const float* b2 = (const float*)d_in[17];
    const float* w3 = (const float*)d_in[18];
    const float* b3 = (const float*)d_in[19];
    float* out = (float*)d_out;

    char* ws = (char*)d_ws;
    const size_t OFF_H    = 0;
    const size_t OFF_XL   = OFF_H + (size_t)N_NODES * 128 * 4;     // bf16 packed: N*64 dwords
    const size_t OFF_XR   = OFF_XL + (size_t)N_NODES * 64 * 4;
    const size_t OFF_PTR  = OFF_XR + (size_t)N_NODES * 128 * 4;
    const size_t OFF_CUR  = OFF_PTR + 120320;
    const size_t OFF_CNT  = OFF_CUR + 120320;
    const size_t OFF_SRC  = OFF_CNT + 120320;
    const size_t OFF_POOL = OFF_SRC + 4120064;
    const size_t OFF_GPTR = OFF_POOL + (size_t)N_GRAPHS * 128 * 4;

    float*    h      = (float*)(ws + OFF_H);
    unsigned* xlb    = (unsigned*)(ws + OFF_XL);
    float*    xr     = (float*)(ws + OFF_XR);
    int*      ptr    = (int*)(ws + OFF_PTR);
    int*      cur    = (int*)(ws + OFF_CUR);
    int*      cnt    = (int*)(ws + OFF_CNT);
    int*      csrsrc = (int*)(ws + OFF_SRC);
    float*    pool   = (float*)(ws + OFF_POOL);
    int*      gptr   = (int*)(ws + OFF_GPTR);

    k_init_cnt<<<(N_NODES + 255) / 256, 256, 0, stream>>>(cnt);
    k_count<<<(N_EDGES + 255) / 256, 256, 0, stream>>>(ei, cnt);
    k_scan<<<1, 1024, 0, stream>>>(cnt, ptr, cur);
    k_fill<<<(ET + 255) / 256, 256, 0, stream>>>(ei, cur, csrsrc);
    k_gptr<<<2, 256, 0, stream>>>(batch, gptr);

    k_inproj<<<(N_NODES * 128 + 255) / 256, 256, 0, stream>>>(x, kp_emb, w_in, b_in, h);

    for (int l = 0; l < LAYERS; ++l) {
        const float* wl = w_l + (size_t)l * 128 * 128;
        const float* wr = w_r + (size_t)l * 128 * 128;
        k_gemm<<<(N_NODES + 63) / 64, 256, 0, stream>>>(h, wl, wr, xlb, xr);
        k_gat<<<(N_NODES + 3) / 4, 256, 0, stream>>>(
            xlb, xr, ptr, csrsrc,
            att + (size_t)l * 128, conv_b + (size_t)l * 128,
            bn_gamma + (size_t)l * 128, bn_beta + (size_t)l * 128,
            bn_mean + (size_t)l * 128, bn_var + (size_t)l * 128, h);
    }

    k_pool_seg<<<N_GRAPHS, 256, 0, stream>>>(h, gptr, pool);
    k_mlp<<<N_GRAPHS, 256, 0, stream>>>(pool, gptr, w1, b1, w2, b2, w3, b3, out);
}